// Round 23
// baseline (34.470 us; speedup 1.0000x reference)
//
#include <hip/hip_runtime.h>
#include <hip/hip_bf16.h>

typedef unsigned short ushort_t;
typedef unsigned int uint_t;
typedef __attribute__((ext_vector_type(8))) short short8;
typedef __attribute__((ext_vector_type(4))) float f32x4;

#define IN_DIM 256
#define OUT_DIM 256
#define BATCH 512
#define NSPL 11
#define KSLOT 12
#define KDIM (IN_DIM * KSLOT)    // 3072
#define BKU 384                  // ushorts per row per chunk (32 inputs x 12)

__device__ __forceinline__ uint_t pk2(float lo, float hi) {
  __hip_bfloat162 h = __float22bfloat162_rn(make_float2(lo, hi));  // v_cvt_pk_bf16_f32, RNE
  union { __hip_bfloat162 h2; uint_t u; } c; c.h2 = h;
  return c.u;
}

// ---- Kernel 1 (R21 best, unchanged): build A and W once; cells assembled in
// LDS, row image written out linearly coalesced. ----
__global__ __launch_bounds__(256) void build_aw(const float* __restrict__ x,
                                                const float* __restrict__ coef,
                                                const float* __restrict__ rw,
                                                const float* __restrict__ uw,
                                                ushort_t* __restrict__ A,
                                                ushort_t* __restrict__ W) {
  __shared__ float rowc[IN_DIM * NSPL];                    // 11.3 KB (W path)
  __shared__ __attribute__((aligned(8))) ushort_t stage[IN_DIM * KSLOT + 8];
  const int bx = blockIdx.x;
  const int t = threadIdx.x;

  if (bx < BATCH) {
    const float xf = x[bx * IN_DIM + t];
    const float tt = (xf + 1.75f) * 4.0f;
    const float fJ = floorf(tt);
    const int J = (int)fJ;
    const float u = tt - fJ;
    const float u2 = u * u, u3 = u2 * u, um = 1.0f - u;
    const float n0 = um * um * um * (1.0f / 6.0f);
    const float n1 = 0.5f * u3 - u2 + (4.0f / 6.0f);
    const float n2 = -0.5f * u3 + 0.5f * u2 + 0.5f * u + (1.0f / 6.0f);
    const float n3 = u3 * (1.0f / 6.0f);
    const float silu = xf / (1.0f + __expf(-xf));

    ushort_t* cb = &stage[t * KSLOT];
    ushort_t* dump = &stage[IN_DIM * KSLOT];
    *(unsigned long long*)&cb[0] = 0ull;
    *(unsigned long long*)&cb[4] = 0ull;
    *(unsigned long long*)&cb[8] = 0ull;

    const uint_t p01 = pk2(n0, n1);
    const uint_t p23 = pk2(n2, n3);
    const uint_t psl = pk2(silu, silu);
    const int base = J - 3;
    ushort_t* w0 = ((unsigned)(base + 0) <= 10u) ? (cb + base + 0) : (dump + 0);
    ushort_t* w1 = ((unsigned)(base + 1) <= 10u) ? (cb + base + 1) : (dump + 1);
    ushort_t* w2 = ((unsigned)(base + 2) <= 10u) ? (cb + base + 2) : (dump + 2);
    ushort_t* w3 = ((unsigned)(base + 3) <= 10u) ? (cb + base + 3) : (dump + 3);
    *w0 = (ushort_t)p01;
    *w1 = (ushort_t)(p01 >> 16);
    *w2 = (ushort_t)p23;
    *w3 = (ushort_t)(p23 >> 16);
    cb[11] = (ushort_t)psl;
    __syncthreads();

    uint_t* dst = (uint_t*)(A + (size_t)bx * KDIM);
    const uint_t* src = (const uint_t*)stage;
#pragma unroll
    for (int p = 0; p < 6; ++p) dst[t + p * 256] = src[t + p * 256];
  } else {
    const int o = bx - BATCH;
    const float* src = coef + (size_t)o * IN_DIM * NSPL;
#pragma unroll
    for (int j = 0; j < 11; ++j) rowc[t + j * 256] = src[t + j * 256];
    __syncthreads();

    const float us = uw[o * IN_DIM + t];
    const float r  = rw[o * IN_DIM + t];
    const float* c = &rowc[t * NSPL];
    uint_t* cell = (uint_t*)&stage[t * KSLOT];
    cell[0] = pk2(us * c[0], us * c[1]);
    cell[1] = pk2(us * c[2], us * c[3]);
    cell[2] = pk2(us * c[4], us * c[5]);
    cell[3] = pk2(us * c[6], us * c[7]);
    cell[4] = pk2(us * c[8], us * c[9]);
    cell[5] = pk2(us * c[10], r);
    __syncthreads();

    uint_t* dst = (uint_t*)(W + (size_t)o * KDIM);
    const uint_t* s2 = (const uint_t*)stage;
#pragma unroll
    for (int p = 0; p < 6; ++p) dst[t + p * 256] = s2[t + p * 256];
  }
}

// ---- Kernel 2 (R21 best, byte-identical): out = A · Wᵀ. IDEMPOTENT — launched
// 4x this round as a timing decomposition probe: Δdur/3 = (k2 + node gap). ----
__global__ __launch_bounds__(256, 3) void gemm(const ushort_t* __restrict__ A,
                                               const ushort_t* __restrict__ W,
                                               float* __restrict__ out) {
  __shared__ __attribute__((aligned(16))) ushort_t As[2][16 * BKU];   // 24.6 KB
  __shared__ __attribute__((aligned(16))) ushort_t Ws[2][16 * BKU];   // 24.6 KB
  __shared__ f32x4 red[3][64];

  const int tid = threadIdx.x;
  const int lane = tid & 63;
  const int w = tid >> 6;                          // wave 0..3 = K-slice owner
  const int B = blockIdx.x;
  const int mt = B >> 4;
  const int nt = ((B & 7) << 1) | ((B >> 3) & 1);  // XCD-aware (bijective, 512%8==0)
  const int b0 = mt * 16, o0 = nt * 16;
  const int mn = lane & 15;
  const int klane = (lane >> 4) * 8;

  int srcOff[3], ldsOff[3];
#pragma unroll
  for (int i = 0; i < 3; ++i) {
    const int F = ((w * 3 + i) * 64 + lane) * 8;
    const int rowi = F / BKU;                      // 0..15
    const int coli = F % BKU;
    srcOff[i] = rowi * KDIM + coli;                // global: linear, coalesced
    ldsOff[i] = rowi * BKU + (coli ^ ((rowi & 7) << 3));   // T2 swizzle (ushort units)
  }
  const ushort_t* Ap = A + (size_t)b0 * KDIM;
  const ushort_t* Wp = W + (size_t)o0 * KDIM;

  const int mrow = mn * BKU;
  const int msw = (mn & 7) << 3;

  f32x4 acc = {0.f, 0.f, 0.f, 0.f};

  short8 s0a0, s0a1, s0a2, s0w0, s0w1, s0w2;
  short8 s1a0, s1a1, s1a2, s1w0, s1w1, s1w2;

#define ISSUE_S0(C) { const int kb = (C) * BKU;                               \
    s0a0 = *(const short8*)(Ap + srcOff[0] + kb);                             \
    s0a1 = *(const short8*)(Ap + srcOff[1] + kb);                             \
    s0a2 = *(const short8*)(Ap + srcOff[2] + kb);                             \
    s0w0 = *(const short8*)(Wp + srcOff[0] + kb);                             \
    s0w1 = *(const short8*)(Wp + srcOff[1] + kb);                             \
    s0w2 = *(const short8*)(Wp + srcOff[2] + kb); }
#define ISSUE_S1(C) { const int kb = (C) * BKU;                               \
    s1a0 = *(const short8*)(Ap + srcOff[0] + kb);                             \
    s1a1 = *(const short8*)(Ap + srcOff[1] + kb);                             \
    s1a2 = *(const short8*)(Ap + srcOff[2] + kb);                             \
    s1w0 = *(const short8*)(Wp + srcOff[0] + kb);                             \
    s1w1 = *(const short8*)(Wp + srcOff[1] + kb);                             \
    s1w2 = *(const short8*)(Wp + srcOff[2] + kb); }
#define COMMIT_S0(BUF) {                                                      \
    *(short8*)&As[BUF][ldsOff[0]] = s0a0;                                     \
    *(short8*)&As[BUF][ldsOff[1]] = s0a1;                                     \
    *(short8*)&As[BUF][ldsOff[2]] = s0a2;                                     \
    *(short8*)&Ws[BUF][ldsOff[0]] = s0w0;                                     \
    *(short8*)&Ws[BUF][ldsOff[1]] = s0w1;                                     \
    *(short8*)&Ws[BUF][ldsOff[2]] = s0w2; }
#define COMMIT_S1(BUF) {                                                      \
    *(short8*)&As[BUF][ldsOff[0]] = s1a0;                                     \
    *(short8*)&As[BUF][ldsOff[1]] = s1a1;                                     \
    *(short8*)&As[BUF][ldsOff[2]] = s1a2;                                     \
    *(short8*)&Ws[BUF][ldsOff[0]] = s1w0;                                     \
    *(short8*)&Ws[BUF][ldsOff[1]] = s1w1;                                     \
    *(short8*)&Ws[BUF][ldsOff[2]] = s1w2; }

#define MFMA3(BUF) { _Pragma("unroll")                                        \
    for (int q = 0; q < 3; ++q) {                                             \
      const int kidx = w * 96 + q * 32 + klane;                               \
      const int idx = mrow + (kidx ^ msw);                                    \
      short8 af  = *(const short8*)&As[BUF][idx];                             \
      short8 bfr = *(const short8*)&Ws[BUF][idx];                             \
      acc = __builtin_amdgcn_mfma_f32_16x16x32_bf16(af, bfr, acc, 0, 0, 0); }}

  ISSUE_S0(0)
  COMMIT_S0(0)
  ISSUE_S1(1)
  __syncthreads();

#pragma unroll
  for (int cc = 0; cc < 4; ++cc) {
    if (cc < 3) { ISSUE_S0(2 * cc + 2) }
    MFMA3(0)
    COMMIT_S1(1)
    __syncthreads();

    if (cc < 3) {
      ISSUE_S1(2 * cc + 3)
      MFMA3(1)
      COMMIT_S0(0)
      __syncthreads();
    } else {
      MFMA3(1)
    }
  }

  if (w > 0) red[w - 1][lane] = acc;
  __syncthreads();

  if (w == 0) {
    const f32x4 t0 = red[0][lane];
    const f32x4 t1 = red[1][lane];
    const f32x4 t2 = red[2][lane];
#pragma unroll
    for (int q = 0; q < 4; ++q) acc[q] += t0[q] + t1[q] + t2[q];

    // C/D layout (HW-verified): col = lane&15, row = (lane>>4)*4 + reg
    const int col = o0 + mn;
    const int rbase = b0 + (lane >> 4) * 4;
#pragma unroll
    for (int r = 0; r < 4; ++r) {
      out[(size_t)(rbase + r) * OUT_DIM + col] = acc[r];
    }
  }
}

extern "C" void kernel_launch(void* const* d_in, const int* in_sizes, int n_in,
                              void* d_out, int out_size, void* d_ws, size_t ws_size,
                              hipStream_t stream) {
  const float* x    = (const float*)d_in[0];
  const float* coef = (const float*)d_in[1];
  const float* rw   = (const float*)d_in[2];
  const float* uw   = (const float*)d_in[3];
  float* out = (float*)d_out;

  ushort_t* A = (ushort_t*)d_ws;                             // 512*3072*2 = 3.0 MB
  ushort_t* W = A + (size_t)BATCH * KDIM;                    // 256*3072*2 = 1.5 MB

  build_aw<<<BATCH + OUT_DIM, 256, 0, stream>>>(x, coef, rw, uw, A, W);
  // PROBE: k2 is idempotent; 4 launches => Δdur/3 = per-(k2+gap) cost.
  gemm<<<512, 256, 0, stream>>>(A, W, out);
  gemm<<<512, 256, 0, stream>>>(A, W, out);
  gemm<<<512, 256, 0, stream>>>(A, W, out);
  gemm<<<512, 256, 0, stream>>>(A, W, out);
}

// Round 24
// 25.223 us; speedup vs baseline: 1.3666x; 1.3666x over previous
//
#include <hip/hip_runtime.h>
#include <hip/hip_bf16.h>

typedef unsigned short ushort_t;
typedef unsigned int uint_t;
typedef __attribute__((ext_vector_type(8))) short short8;
typedef __attribute__((ext_vector_type(4))) float f32x4;

#define IN_DIM 256
#define OUT_DIM 256
#define BATCH 512
#define NSPL 11
#define KSLOT 12
#define KDIM (IN_DIM * KSLOT)    // 3072
#define BKU 384                  // ushorts per row per chunk (32 inputs x 12)

__device__ __forceinline__ uint_t pk2(float lo, float hi) {
  __hip_bfloat162 h = __float22bfloat162_rn(make_float2(lo, hi));  // v_cvt_pk_bf16_f32, RNE
  union { __hip_bfloat162 h2; uint_t u; } c; c.h2 = h;
  return c.u;
}

// ---- Kernel 1 (R21 best, byte-identical): build A and W once. IDEMPOTENT —
// launched 4x this round as the complementary decomposition probe. ----
__global__ __launch_bounds__(256) void build_aw(const float* __restrict__ x,
                                                const float* __restrict__ coef,
                                                const float* __restrict__ rw,
                                                const float* __restrict__ uw,
                                                ushort_t* __restrict__ A,
                                                ushort_t* __restrict__ W) {
  __shared__ float rowc[IN_DIM * NSPL];                    // 11.3 KB (W path)
  __shared__ __attribute__((aligned(8))) ushort_t stage[IN_DIM * KSLOT + 8];
  const int bx = blockIdx.x;
  const int t = threadIdx.x;

  if (bx < BATCH) {
    const float xf = x[bx * IN_DIM + t];
    const float tt = (xf + 1.75f) * 4.0f;
    const float fJ = floorf(tt);
    const int J = (int)fJ;
    const float u = tt - fJ;
    const float u2 = u * u, u3 = u2 * u, um = 1.0f - u;
    const float n0 = um * um * um * (1.0f / 6.0f);
    const float n1 = 0.5f * u3 - u2 + (4.0f / 6.0f);
    const float n2 = -0.5f * u3 + 0.5f * u2 + 0.5f * u + (1.0f / 6.0f);
    const float n3 = u3 * (1.0f / 6.0f);
    const float silu = xf / (1.0f + __expf(-xf));

    ushort_t* cb = &stage[t * KSLOT];
    ushort_t* dump = &stage[IN_DIM * KSLOT];
    *(unsigned long long*)&cb[0] = 0ull;
    *(unsigned long long*)&cb[4] = 0ull;
    *(unsigned long long*)&cb[8] = 0ull;

    const uint_t p01 = pk2(n0, n1);
    const uint_t p23 = pk2(n2, n3);
    const uint_t psl = pk2(silu, silu);
    const int base = J - 3;
    ushort_t* w0 = ((unsigned)(base + 0) <= 10u) ? (cb + base + 0) : (dump + 0);
    ushort_t* w1 = ((unsigned)(base + 1) <= 10u) ? (cb + base + 1) : (dump + 1);
    ushort_t* w2 = ((unsigned)(base + 2) <= 10u) ? (cb + base + 2) : (dump + 2);
    ushort_t* w3 = ((unsigned)(base + 3) <= 10u) ? (cb + base + 3) : (dump + 3);
    *w0 = (ushort_t)p01;
    *w1 = (ushort_t)(p01 >> 16);
    *w2 = (ushort_t)p23;
    *w3 = (ushort_t)(p23 >> 16);
    cb[11] = (ushort_t)psl;
    __syncthreads();

    uint_t* dst = (uint_t*)(A + (size_t)bx * KDIM);
    const uint_t* src = (const uint_t*)stage;
#pragma unroll
    for (int p = 0; p < 6; ++p) dst[t + p * 256] = src[t + p * 256];
  } else {
    const int o = bx - BATCH;
    const float* src = coef + (size_t)o * IN_DIM * NSPL;
#pragma unroll
    for (int j = 0; j < 11; ++j) rowc[t + j * 256] = src[t + j * 256];
    __syncthreads();

    const float us = uw[o * IN_DIM + t];
    const float r  = rw[o * IN_DIM + t];
    const float* c = &rowc[t * NSPL];
    uint_t* cell = (uint_t*)&stage[t * KSLOT];
    cell[0] = pk2(us * c[0], us * c[1]);
    cell[1] = pk2(us * c[2], us * c[3]);
    cell[2] = pk2(us * c[4], us * c[5]);
    cell[3] = pk2(us * c[6], us * c[7]);
    cell[4] = pk2(us * c[8], us * c[9]);
    cell[5] = pk2(us * c[10], r);
    __syncthreads();

    uint_t* dst = (uint_t*)(W + (size_t)o * KDIM);
    const uint_t* s2 = (const uint_t*)stage;
#pragma unroll
    for (int p = 0; p < 6; ++p) dst[t + p * 256] = s2[t + p * 256];
  }
}

// ---- Kernel 2 (R21 best, byte-identical): out = A · Wᵀ. ----
__global__ __launch_bounds__(256, 3) void gemm(const ushort_t* __restrict__ A,
                                               const ushort_t* __restrict__ W,
                                               float* __restrict__ out) {
  __shared__ __attribute__((aligned(16))) ushort_t As[2][16 * BKU];   // 24.6 KB
  __shared__ __attribute__((aligned(16))) ushort_t Ws[2][16 * BKU];   // 24.6 KB
  __shared__ f32x4 red[3][64];

  const int tid = threadIdx.x;
  const int lane = tid & 63;
  const int w = tid >> 6;                          // wave 0..3 = K-slice owner
  const int B = blockIdx.x;
  const int mt = B >> 4;
  const int nt = ((B & 7) << 1) | ((B >> 3) & 1);  // XCD-aware (bijective, 512%8==0)
  const int b0 = mt * 16, o0 = nt * 16;
  const int mn = lane & 15;
  const int klane = (lane >> 4) * 8;

  int srcOff[3], ldsOff[3];
#pragma unroll
  for (int i = 0; i < 3; ++i) {
    const int F = ((w * 3 + i) * 64 + lane) * 8;
    const int rowi = F / BKU;                      // 0..15
    const int coli = F % BKU;
    srcOff[i] = rowi * KDIM + coli;                // global: linear, coalesced
    ldsOff[i] = rowi * BKU + (coli ^ ((rowi & 7) << 3));   // T2 swizzle (ushort units)
  }
  const ushort_t* Ap = A + (size_t)b0 * KDIM;
  const ushort_t* Wp = W + (size_t)o0 * KDIM;

  const int mrow = mn * BKU;
  const int msw = (mn & 7) << 3;

  f32x4 acc = {0.f, 0.f, 0.f, 0.f};

  short8 s0a0, s0a1, s0a2, s0w0, s0w1, s0w2;
  short8 s1a0, s1a1, s1a2, s1w0, s1w1, s1w2;

#define ISSUE_S0(C) { const int kb = (C) * BKU;                               \
    s0a0 = *(const short8*)(Ap + srcOff[0] + kb);                             \
    s0a1 = *(const short8*)(Ap + srcOff[1] + kb);                             \
    s0a2 = *(const short8*)(Ap + srcOff[2] + kb);                             \
    s0w0 = *(const short8*)(Wp + srcOff[0] + kb);                             \
    s0w1 = *(const short8*)(Wp + srcOff[1] + kb);                             \
    s0w2 = *(const short8*)(Wp + srcOff[2] + kb); }
#define ISSUE_S1(C) { const int kb = (C) * BKU;                               \
    s1a0 = *(const short8*)(Ap + srcOff[0] + kb);                             \
    s1a1 = *(const short8*)(Ap + srcOff[1] + kb);                             \
    s1a2 = *(const short8*)(Ap + srcOff[2] + kb);                             \
    s1w0 = *(const short8*)(Wp + srcOff[0] + kb);                             \
    s1w1 = *(const short8*)(Wp + srcOff[1] + kb);                             \
    s1w2 = *(const short8*)(Wp + srcOff[2] + kb); }
#define COMMIT_S0(BUF) {                                                      \
    *(short8*)&As[BUF][ldsOff[0]] = s0a0;                                     \
    *(short8*)&As[BUF][ldsOff[1]] = s0a1;                                     \
    *(short8*)&As[BUF][ldsOff[2]] = s0a2;                                     \
    *(short8*)&Ws[BUF][ldsOff[0]] = s0w0;                                     \
    *(short8*)&Ws[BUF][ldsOff[1]] = s0w1;                                     \
    *(short8*)&Ws[BUF][ldsOff[2]] = s0w2; }
#define COMMIT_S1(BUF) {                                                      \
    *(short8*)&As[BUF][ldsOff[0]] = s1a0;                                     \
    *(short8*)&As[BUF][ldsOff[1]] = s1a1;                                     \
    *(short8*)&As[BUF][ldsOff[2]] = s1a2;                                     \
    *(short8*)&Ws[BUF][ldsOff[0]] = s1w0;                                     \
    *(short8*)&Ws[BUF][ldsOff[1]] = s1w1;                                     \
    *(short8*)&Ws[BUF][ldsOff[2]] = s1w2; }

#define MFMA3(BUF) { _Pragma("unroll")                                        \
    for (int q = 0; q < 3; ++q) {                                             \
      const int kidx = w * 96 + q * 32 + klane;                               \
      const int idx = mrow + (kidx ^ msw);                                    \
      short8 af  = *(const short8*)&As[BUF][idx];                             \
      short8 bfr = *(const short8*)&Ws[BUF][idx];                             \
      acc = __builtin_amdgcn_mfma_f32_16x16x32_bf16(af, bfr, acc, 0, 0, 0); }}

  ISSUE_S0(0)
  COMMIT_S0(0)
  ISSUE_S1(1)
  __syncthreads();

#pragma unroll
  for (int cc = 0; cc < 4; ++cc) {
    if (cc < 3) { ISSUE_S0(2 * cc + 2) }
    MFMA3(0)
    COMMIT_S1(1)
    __syncthreads();

    if (cc < 3) {
      ISSUE_S1(2 * cc + 3)
      MFMA3(1)
      COMMIT_S0(0)
      __syncthreads();
    } else {
      MFMA3(1)
    }
  }

  if (w > 0) red[w - 1][lane] = acc;
  __syncthreads();

  if (w == 0) {
    const f32x4 t0 = red[0][lane];
    const f32x4 t1 = red[1][lane];
    const f32x4 t2 = red[2][lane];
#pragma unroll
    for (int q = 0; q < 4; ++q) acc[q] += t0[q] + t1[q] + t2[q];

    // C/D layout (HW-verified): col = lane&15, row = (lane>>4)*4 + reg
    const int col = o0 + mn;
    const int rbase = b0 + (lane >> 4) * 4;
#pragma unroll
    for (int r = 0; r < 4; ++r) {
      out[(size_t)(rbase + r) * OUT_DIM + col] = acc[r];
    }
  }
}

extern "C" void kernel_launch(void* const* d_in, const int* in_sizes, int n_in,
                              void* d_out, int out_size, void* d_ws, size_t ws_size,
                              hipStream_t stream) {
  const float* x    = (const float*)d_in[0];
  const float* coef = (const float*)d_in[1];
  const float* rw   = (const float*)d_in[2];
  const float* uw   = (const float*)d_in[3];
  float* out = (float*)d_out;

  ushort_t* A = (ushort_t*)d_ws;                             // 512*3072*2 = 3.0 MB
  ushort_t* W = A + (size_t)BATCH * KDIM;                    // 256*3072*2 = 1.5 MB

  // PROBE: k1 is idempotent; 4 launches => Δdur/3 vs R21 = per-(k1+gap) cost.
  build_aw<<<BATCH + OUT_DIM, 256, 0, stream>>>(x, coef, rw, uw, A, W);
  build_aw<<<BATCH + OUT_DIM, 256, 0, stream>>>(x, coef, rw, uw, A, W);
  build_aw<<<BATCH + OUT_DIM, 256, 0, stream>>>(x, coef, rw, uw, A, W);
  build_aw<<<BATCH + OUT_DIM, 256, 0, stream>>>(x, coef, rw, uw, A, W);
  gemm<<<512, 256, 0, stream>>>(A, W, out);
}

// Round 25
// 16.472 us; speedup vs baseline: 2.0926x; 1.5312x over previous
//
#include <hip/hip_runtime.h>
#include <hip/hip_bf16.h>

typedef unsigned short ushort_t;
typedef unsigned int uint_t;
typedef __attribute__((ext_vector_type(8))) short short8;
typedef __attribute__((ext_vector_type(4))) float f32x4;

#define IN_DIM 256
#define OUT_DIM 256
#define BATCH 512
#define NSPL 11
#define KSLOT 12
#define KDIM (IN_DIM * KSLOT)    // 3072
#define BKU 384                  // ushorts per row per chunk (32 inputs x 12)

__device__ __forceinline__ uint_t pk2(float lo, float hi) {
  __hip_bfloat162 h = __float22bfloat162_rn(make_float2(lo, hi));  // v_cvt_pk_bf16_f32, RNE
  union { __hip_bfloat162 h2; uint_t u; } c; c.h2 = h;
  return c.u;
}

// ---- Kernel 1: build A and W once (R21 structure). A-row assignment is
// XCD-ALIGNED with k2's consumption: block bx (on XCD bx%8 under round-robin
// dispatch) builds A row (bx&7)*64 + (bx>>3), so the rows XCD x consumes in k2
// ([64x, 64x+64)) are produced on XCD x -> cold reads hit the local L2. ----
__global__ __launch_bounds__(256) void build_aw(const float* __restrict__ x,
                                                const float* __restrict__ coef,
                                                const float* __restrict__ rw,
                                                const float* __restrict__ uw,
                                                ushort_t* __restrict__ A,
                                                ushort_t* __restrict__ W) {
  __shared__ float rowc[IN_DIM * NSPL];                    // 11.3 KB (W path)
  __shared__ __attribute__((aligned(8))) ushort_t stage[IN_DIM * KSLOT + 8];
  const int bx = blockIdx.x;
  const int t = threadIdx.x;

  if (bx < BATCH) {
    const int row = ((bx & 7) << 6) | (bx >> 3);           // XCD-local A row (bijective)
    const float xf = x[row * IN_DIM + t];
    const float tt = (xf + 1.75f) * 4.0f;
    const float fJ = floorf(tt);
    const int J = (int)fJ;
    const float u = tt - fJ;
    const float u2 = u * u, u3 = u2 * u, um = 1.0f - u;
    const float n0 = um * um * um * (1.0f / 6.0f);
    const float n1 = 0.5f * u3 - u2 + (4.0f / 6.0f);
    const float n2 = -0.5f * u3 + 0.5f * u2 + 0.5f * u + (1.0f / 6.0f);
    const float n3 = u3 * (1.0f / 6.0f);
    const float silu = xf / (1.0f + __expf(-xf));

    ushort_t* cb = &stage[t * KSLOT];
    ushort_t* dump = &stage[IN_DIM * KSLOT];
    *(unsigned long long*)&cb[0] = 0ull;
    *(unsigned long long*)&cb[4] = 0ull;
    *(unsigned long long*)&cb[8] = 0ull;

    const uint_t p01 = pk2(n0, n1);
    const uint_t p23 = pk2(n2, n3);
    const uint_t psl = pk2(silu, silu);
    const int base = J - 3;
    ushort_t* w0 = ((unsigned)(base + 0) <= 10u) ? (cb + base + 0) : (dump + 0);
    ushort_t* w1 = ((unsigned)(base + 1) <= 10u) ? (cb + base + 1) : (dump + 1);
    ushort_t* w2 = ((unsigned)(base + 2) <= 10u) ? (cb + base + 2) : (dump + 2);
    ushort_t* w3 = ((unsigned)(base + 3) <= 10u) ? (cb + base + 3) : (dump + 3);
    *w0 = (ushort_t)p01;
    *w1 = (ushort_t)(p01 >> 16);
    *w2 = (ushort_t)p23;
    *w3 = (ushort_t)(p23 >> 16);
    cb[11] = (ushort_t)psl;
    __syncthreads();

    uint_t* dst = (uint_t*)(A + (size_t)row * KDIM);
    const uint_t* src = (const uint_t*)stage;
#pragma unroll
    for (int p = 0; p < 6; ++p) dst[t + p * 256] = src[t + p * 256];
  } else {
    const int o = bx - BATCH;
    const float* src = coef + (size_t)o * IN_DIM * NSPL;
#pragma unroll
    for (int j = 0; j < 11; ++j) rowc[t + j * 256] = src[t + j * 256];
    __syncthreads();

    const float us = uw[o * IN_DIM + t];
    const float r  = rw[o * IN_DIM + t];
    const float* c = &rowc[t * NSPL];
    uint_t* cell = (uint_t*)&stage[t * KSLOT];
    cell[0] = pk2(us * c[0], us * c[1]);
    cell[1] = pk2(us * c[2], us * c[3]);
    cell[2] = pk2(us * c[4], us * c[5]);
    cell[3] = pk2(us * c[6], us * c[7]);
    cell[4] = pk2(us * c[8], us * c[9]);
    cell[5] = pk2(us * c[10], r);
    __syncthreads();

    uint_t* dst = (uint_t*)(W + (size_t)o * KDIM);
    const uint_t* s2 = (const uint_t*)stage;
#pragma unroll
    for (int p = 0; p < 6; ++p) dst[t + p * 256] = s2[t + p * 256];
  }
}

// ---- Kernel 2: out = A · Wᵀ (R21-best pipeline, byte-identical loop). Tile map
// is XCD-CONTIGUOUS in M: XCD x (B%8) covers mt in [4x,4x+4) x all nt — so each
// XCD reads only 64 A-rows (384 KB, L2-captive; produced locally by k1). ----
__global__ __launch_bounds__(256, 3) void gemm(const ushort_t* __restrict__ A,
                                               const ushort_t* __restrict__ W,
                                               float* __restrict__ out) {
  __shared__ __attribute__((aligned(16))) ushort_t As[2][16 * BKU];   // 24.6 KB
  __shared__ __attribute__((aligned(16))) ushort_t Ws[2][16 * BKU];   // 24.6 KB
  __shared__ f32x4 red[3][64];

  const int tid = threadIdx.x;
  const int lane = tid & 63;
  const int w = tid >> 6;                          // wave 0..3 = K-slice owner
  const int B = blockIdx.x;
  const int mt = ((B & 7) << 2) | (B >> 7);        // XCD-contiguous M (bijective)
  const int nt = (B >> 3) & 15;
  const int b0 = mt * 16, o0 = nt * 16;
  const int mn = lane & 15;
  const int klane = (lane >> 4) * 8;

  int srcOff[3], ldsOff[3];
#pragma unroll
  for (int i = 0; i < 3; ++i) {
    const int F = ((w * 3 + i) * 64 + lane) * 8;
    const int rowi = F / BKU;                      // 0..15
    const int coli = F % BKU;
    srcOff[i] = rowi * KDIM + coli;                // global: linear, coalesced
    ldsOff[i] = rowi * BKU + (coli ^ ((rowi & 7) << 3));   // T2 swizzle (ushort units)
  }
  const ushort_t* Ap = A + (size_t)b0 * KDIM;
  const ushort_t* Wp = W + (size_t)o0 * KDIM;

  const int mrow = mn * BKU;
  const int msw = (mn & 7) << 3;

  f32x4 acc = {0.f, 0.f, 0.f, 0.f};

  short8 s0a0, s0a1, s0a2, s0w0, s0w1, s0w2;
  short8 s1a0, s1a1, s1a2, s1w0, s1w1, s1w2;

#define ISSUE_S0(C) { const int kb = (C) * BKU;                               \
    s0a0 = *(const short8*)(Ap + srcOff[0] + kb);                             \
    s0a1 = *(const short8*)(Ap + srcOff[1] + kb);                             \
    s0a2 = *(const short8*)(Ap + srcOff[2] + kb);                             \
    s0w0 = *(const short8*)(Wp + srcOff[0] + kb);                             \
    s0w1 = *(const short8*)(Wp + srcOff[1] + kb);                             \
    s0w2 = *(const short8*)(Wp + srcOff[2] + kb); }
#define ISSUE_S1(C) { const int kb = (C) * BKU;                               \
    s1a0 = *(const short8*)(Ap + srcOff[0] + kb);                             \
    s1a1 = *(const short8*)(Ap + srcOff[1] + kb);                             \
    s1a2 = *(const short8*)(Ap + srcOff[2] + kb);                             \
    s1w0 = *(const short8*)(Wp + srcOff[0] + kb);                             \
    s1w1 = *(const short8*)(Wp + srcOff[1] + kb);                             \
    s1w2 = *(const short8*)(Wp + srcOff[2] + kb); }
#define COMMIT_S0(BUF) {                                                      \
    *(short8*)&As[BUF][ldsOff[0]] = s0a0;                                     \
    *(short8*)&As[BUF][ldsOff[1]] = s0a1;                                     \
    *(short8*)&As[BUF][ldsOff[2]] = s0a2;                                     \
    *(short8*)&Ws[BUF][ldsOff[0]] = s0w0;                                     \
    *(short8*)&Ws[BUF][ldsOff[1]] = s0w1;                                     \
    *(short8*)&Ws[BUF][ldsOff[2]] = s0w2; }
#define COMMIT_S1(BUF) {                                                      \
    *(short8*)&As[BUF][ldsOff[0]] = s1a0;                                     \
    *(short8*)&As[BUF][ldsOff[1]] = s1a1;                                     \
    *(short8*)&As[BUF][ldsOff[2]] = s1a2;                                     \
    *(short8*)&Ws[BUF][ldsOff[0]] = s1w0;                                     \
    *(short8*)&Ws[BUF][ldsOff[1]] = s1w1;                                     \
    *(short8*)&Ws[BUF][ldsOff[2]] = s1w2; }

#define MFMA3(BUF) { _Pragma("unroll")                                        \
    for (int q = 0; q < 3; ++q) {                                             \
      const int kidx = w * 96 + q * 32 + klane;                               \
      const int idx = mrow + (kidx ^ msw);                                    \
      short8 af  = *(const short8*)&As[BUF][idx];                             \
      short8 bfr = *(const short8*)&Ws[BUF][idx];                             \
      acc = __builtin_amdgcn_mfma_f32_16x16x32_bf16(af, bfr, acc, 0, 0, 0); }}

  ISSUE_S0(0)
  COMMIT_S0(0)
  ISSUE_S1(1)
  __syncthreads();

#pragma unroll
  for (int cc = 0; cc < 4; ++cc) {
    if (cc < 3) { ISSUE_S0(2 * cc + 2) }
    MFMA3(0)
    COMMIT_S1(1)
    __syncthreads();

    if (cc < 3) {
      ISSUE_S1(2 * cc + 3)
      MFMA3(1)
      COMMIT_S0(0)
      __syncthreads();
    } else {
      MFMA3(1)
    }
  }

  if (w > 0) red[w - 1][lane] = acc;
  __syncthreads();

  if (w == 0) {
    const f32x4 t0 = red[0][lane];
    const f32x4 t1 = red[1][lane];
    const f32x4 t2 = red[2][lane];
#pragma unroll
    for (int q = 0; q < 4; ++q) acc[q] += t0[q] + t1[q] + t2[q];

    // C/D layout (HW-verified): col = lane&15, row = (lane>>4)*4 + reg
    const int col = o0 + mn;
    const int rbase = b0 + (lane >> 4) * 4;
#pragma unroll
    for (int r = 0; r < 4; ++r) {
      out[(size_t)(rbase + r) * OUT_DIM + col] = acc[r];
    }
  }
}

extern "C" void kernel_launch(void* const* d_in, const int* in_sizes, int n_in,
                              void* d_out, int out_size, void* d_ws, size_t ws_size,
                              hipStream_t stream) {
  const float* x    = (const float*)d_in[0];
  const float* coef = (const float*)d_in[1];
  const float* rw   = (const float*)d_in[2];
  const float* uw   = (const float*)d_in[3];
  float* out = (float*)d_out;

  ushort_t* A = (ushort_t*)d_ws;                             // 512*3072*2 = 3.0 MB
  ushort_t* W = A + (size_t)BATCH * KDIM;                    // 256*3072*2 = 1.5 MB

  build_aw<<<BATCH + OUT_DIM, 256, 0, stream>>>(x, coef, rw, uw, A, W);
  gemm<<<512, 256, 0, stream>>>(A, W, out);
}